// Round 5
// baseline (1219.694 us; speedup 1.0000x reference)
//
#include <hip/hip_runtime.h>
#include <cstdint>

typedef _Float16 f16x8 __attribute__((ext_vector_type(8)));
typedef float f32x4 __attribute__((ext_vector_type(4)));

#define MDIM 24000   // N*T rows
#define DDIM 1024
#define CDIM 20
#define TDIM 750
#define NBATCH 32
#define KSEL 657
#define MASKV -100.0f
#define OMEGAF 0.6f
#define SPLIT_SCALE 2048.0f
#define SPLIT_INV   4.8828125e-4f   // 2^-11 exact

// d_out element offsets (x_r, cls_x_r, cls_x_ra, x_f, cls_x_f, cls_x_fa, tcam)
#define OFF_XR     0L
#define OFF_CLSX_R 24576000L
#define OFF_CLSRA  25056000L
#define OFF_XF     25536000L
#define OFF_CLSX_F 50112000L
#define OFF_CLSFA  50592000L
#define OFF_TCAM   51072000L

#define GLOAD16(g, l) __builtin_amdgcn_global_load_lds( \
    (const __attribute__((address_space(1))) void*)(g), \
    (__attribute__((address_space(3))) void*)(l), 16, 0, 0)

// ---------------------------------------------------------------------------
// split helpers
// ---------------------------------------------------------------------------
__global__ __launch_bounds__(256)
void split_f16(const float* __restrict__ src, long srcStride, long nrows,
               _Float16* __restrict__ D0, _Float16* __restrict__ D1) {
    const long nvec = nrows * 128;
    for (long v = (long)blockIdx.x * 256 + threadIdx.x; v < nvec; v += (long)gridDim.x * 256) {
        const long row = v >> 7;
        const int c8 = (int)(v & 127) << 3;
        const float4 x0 = *reinterpret_cast<const float4*>(&src[row * srcStride + c8]);
        const float4 x1 = *reinterpret_cast<const float4*>(&src[row * srcStride + c8 + 4]);
        float xs[8] = {x0.x, x0.y, x0.z, x0.w, x1.x, x1.y, x1.z, x1.w};
        f16x8 h0, h1;
#pragma unroll
        for (int j = 0; j < 8; ++j) {
            const _Float16 a = (_Float16)xs[j];
            h0[j] = a;
            h1[j] = (_Float16)((xs[j] - (float)a) * SPLIT_SCALE);
        }
        *reinterpret_cast<f16x8*>(&D0[v << 3]) = h0;
        *reinterpret_cast<f16x8*>(&D1[v << 3]) = h1;
    }
}

// ---------------------------------------------------------------------------
// 128x128 split-f16 MFMA GEMM (m97 structure), K' = 3x1024.
// 256 threads = 4 waves (2x2); per-wave 64x64 out; BK=64; LDS 32 KiB.
// LDS layout: 16x32-f16 subtiles (1024B): one global_load_lds wave-issue
// fills one subtile; one MFMA fragment read = one whole subtile (bijective,
// conflict-minimal). ~3 blocks/CU co-resident hide the syncthreads drain.
// ---------------------------------------------------------------------------
__device__ __forceinline__ void stage_tile(_Float16* dst, const _Float16* base,
                                           long row0, long rmax, int k0,
                                           int wv, int lane) {
#pragma unroll
    for (int h = 0; h < 2; ++h) {
        const int rb = wv * 2 + h;                 // subtile row-block 0..7
        long r = row0 + rb * 16 + (lane >> 2);
        if (r > rmax) r = rmax;
        const _Float16* g = base + (r << 10) + k0 + ((lane & 3) << 3);
#pragma unroll
        for (int kk = 0; kk < 2; ++kk)
            GLOAD16(g + kk * 32, dst + (rb * 2 + kk) * 512);
    }
}

template<int MODE>
__global__ __launch_bounds__(256)
void gemm_split_f16(const _Float16* __restrict__ A0, const _Float16* __restrict__ A1,
                    const _Float16* __restrict__ B0, const _Float16* __restrict__ B1,
                    const float* __restrict__ bias,
                    float* __restrict__ outF,
                    _Float16* __restrict__ H0, _Float16* __restrict__ H1) {
    __shared__ _Float16 As[8192];   // 8 rb x 2 kk subtiles of 512 f16
    __shared__ _Float16 Bs[8192];
    const int t = threadIdx.x;
    const int lane = t & 63;
    const int wave = t >> 6;
    const int wr = wave >> 1, wc = wave & 1;
    const int lr = lane & 15, lk = lane >> 4;
    const long bm = (long)blockIdx.x * 128;
    const int bn = blockIdx.y * 128;

    f32x4 acc[4][4];
#pragma unroll
    for (int mi = 0; mi < 4; ++mi)
#pragma unroll
        for (int ni = 0; ni < 4; ++ni)
            acc[mi][ni] = (f32x4){0.f, 0.f, 0.f, 0.f};

#define LDSA(rb, kk) (*(const f16x8*)&As[((rb) * 2 + (kk)) * 512 + lr * 32 + lk * 8])
#define LDSB(rb, kk) (*(const f16x8*)&Bs[((rb) * 2 + (kk)) * 512 + lr * 32 + lk * 8])

    for (int step = 0; step < 48; ++step) {
        const int p = step >> 4;
        const int k0 = (step & 15) << 6;
        const _Float16* __restrict__ Ab = (p == 1) ? A1 : A0;
        const _Float16* __restrict__ Bb = (p == 0) ? B1 : B0;
        if (step == 32) {   // exact 2^-11 rescale of the two lo-panels
#pragma unroll
            for (int mi = 0; mi < 4; ++mi)
#pragma unroll
                for (int ni = 0; ni < 4; ++ni)
                    acc[mi][ni] *= SPLIT_INV;
        }
        __syncthreads();   // prior step's LDS reads complete before overwrite
        stage_tile(As, Ab, bm, (long)(MDIM - 1), k0, wave, lane);
        stage_tile(Bs, Bb, (long)bn, 1023L, k0, wave, lane);
        __syncthreads();   // drains global_load_lds (vmcnt0) + visibility
#pragma unroll
        for (int kc = 0; kc < 2; ++kc) {
            f16x8 av[4], bv[4];
#pragma unroll
            for (int mi = 0; mi < 4; ++mi) av[mi] = LDSA(wr * 4 + mi, kc);
#pragma unroll
            for (int ni = 0; ni < 4; ++ni) bv[ni] = LDSB(wc * 4 + ni, kc);
#pragma unroll
            for (int mi = 0; mi < 4; ++mi)
#pragma unroll
                for (int ni = 0; ni < 4; ++ni)
                    acc[mi][ni] = __builtin_amdgcn_mfma_f32_16x16x32_f16(av[mi], bv[ni], acc[mi][ni], 0, 0, 0);
        }
    }

    // epilogue: C/D layout col=lane&15, row=(lane>>4)*4+r (verified r2/r4)
#pragma unroll
    for (int ni = 0; ni < 4; ++ni) {
        const int col = bn + wc * 64 + ni * 16 + lr;
        const float bb = bias[col];
#pragma unroll
        for (int mi = 0; mi < 4; ++mi) {
            const long rbase = bm + wr * 64 + mi * 16 + lk * 4;
#pragma unroll
            for (int r = 0; r < 4; ++r) {
                const long row = rbase + r;
                if (row < MDIM) {
                    const float hv = fmaxf(acc[mi][ni][r] + bb, 0.f);
                    if (MODE == 0) {
                        const _Float16 h0 = (_Float16)hv;
                        H0[row * DDIM + col] = h0;
                        H1[row * DDIM + col] = (_Float16)((hv - (float)h0) * SPLIT_SCALE);
                    } else {
                        outF[row * DDIM + col] = hv;
                    }
                }
            }
        }
    }
#undef LDSA
#undef LDSB
}

// ---------------------------------------------------------------------------
// cls/at heads in fp32 (precision-critical for the top-k mask), N padded to 48.
// ---------------------------------------------------------------------------
__global__ __launch_bounds__(256)
void cls_gemm_f32(const float* __restrict__ H,
                  const float* __restrict__ Wc, const float* __restrict__ bc,
                  const float* __restrict__ Wa, const float* __restrict__ ba,
                  float* __restrict__ clsx, float* __restrict__ atout) {
    __shared__ float As[16][140];
    __shared__ float Bs[16][48];
    const int tid = threadIdx.x;
    const int tx = tid & 15, ty = tid >> 4;
    const long bm = (long)blockIdx.x * 128;

    float acc[8][3];
#pragma unroll
    for (int i = 0; i < 8; ++i)
#pragma unroll
        for (int j = 0; j < 3; ++j) acc[i][j] = 0.f;

    for (int k0 = 0; k0 < DDIM; k0 += 16) {
        __syncthreads();
#pragma unroll
        for (int h = 0; h < 2; ++h) {
            const int c = tid + h * 256;
            const int row = c >> 2;
            const int kc = (c & 3) << 2;
            long ar = bm + row; if (ar > MDIM - 1) ar = MDIM - 1;
            const float4 va = *reinterpret_cast<const float4*>(&H[ar * DDIM + k0 + kc]);
            As[kc + 0][row] = va.x; As[kc + 1][row] = va.y;
            As[kc + 2][row] = va.z; As[kc + 3][row] = va.w;
        }
        if (tid < 192) {
            const int n = tid >> 2;
            const int kc = (tid & 3) << 2;
            float4 w = make_float4(0.f, 0.f, 0.f, 0.f);
            if (n < 20)      w = *reinterpret_cast<const float4*>(&Wc[(long)n * DDIM + k0 + kc]);
            else if (n < 40) w = *reinterpret_cast<const float4*>(&Wa[(long)(n - 20) * DDIM + k0 + kc]);
            Bs[kc + 0][n] = w.x; Bs[kc + 1][n] = w.y;
            Bs[kc + 2][n] = w.z; Bs[kc + 3][n] = w.w;
        }
        __syncthreads();
#pragma unroll
        for (int kk = 0; kk < 16; ++kk) {
            float a[8];
            *(float4*)&a[0] = *(const float4*)&As[kk][ty * 8];
            *(float4*)&a[4] = *(const float4*)&As[kk][ty * 8 + 4];
            const float b0 = Bs[kk][tx];
            const float b1 = Bs[kk][tx + 16];
            const float b2 = Bs[kk][tx + 32];
#pragma unroll
            for (int i = 0; i < 8; ++i) {
                acc[i][0] = fmaf(a[i], b0, acc[i][0]);
                acc[i][1] = fmaf(a[i], b1, acc[i][1]);
                acc[i][2] = fmaf(a[i], b2, acc[i][2]);
            }
        }
    }

#pragma unroll
    for (int j = 0; j < 3; ++j) {
        const int col = tx + 16 * j;
        const bool isC = (col < 20);
        const bool isA = (col >= 20) && (col < 40);
        const float bvv = isC ? bc[col] : (isA ? ba[col - 20] : 0.f);
#pragma unroll
        for (int i = 0; i < 8; ++i) {
            const long row = bm + ty * 8 + i;
            if (row < MDIM) {
                const float v = acc[i][j] + bvv;
                if (isC)      clsx[row * CDIM + col] = v;
                else if (isA) atout[row * CDIM + col - 20] = v;
            }
        }
    }
}

// Per (stream,n,c): bitonic sort 750 values (pad to 1024 with +inf), emit rank KSEL.
__global__ __launch_bounds__(512)
void select_kth(const float* __restrict__ clsx_r, const float* __restrict__ clsx_f,
                float* __restrict__ kth) {
    __shared__ float s[1024];
    const int b = blockIdx.x;
    const int z = b / 640;
    const int rem = b - z * 640;
    const int n = rem / CDIM;
    const int c = rem - n * CDIM;
    const float* src = (z == 0) ? clsx_r : clsx_f;
    const int tid = threadIdx.x;

    for (int i = tid; i < 1024; i += 512)
        s[i] = (i < TDIM) ? src[((long)n * TDIM + i) * CDIM + c] : 3.402823466e38f;
    __syncthreads();

    for (int k = 2; k <= 1024; k <<= 1) {
        for (int j = k >> 1; j > 0; j >>= 1) {
            for (int i = tid; i < 1024; i += 512) {
                const int ixj = i ^ j;
                if (ixj > i) {
                    const bool up = ((i & k) == 0);
                    const float x = s[i], y = s[ixj];
                    if ((x > y) == up) { s[i] = y; s[ixj] = x; }
                }
            }
            __syncthreads();
        }
    }
    if (tid == 0) kth[b] = s[KSEL - 1];
}

__global__ __launch_bounds__(256)
void final_mask(float* __restrict__ out, const float* __restrict__ kth,
                const float* __restrict__ mul_r, const float* __restrict__ mul_f) {
    const int idx = blockIdx.x * 256 + threadIdx.x;
    if (idx >= NBATCH * TDIM * CDIM) return;
    const int m = idx / CDIM;
    const int c = idx - m * CDIM;
    const int n = m / TDIM;
    const float xr  = out[OFF_CLSX_R + idx];
    const float xf  = out[OFF_CLSX_F + idx];
    const float atr = out[OFF_CLSRA + idx];
    const float atf = out[OFF_CLSFA + idx];
    const float kr = kth[n * CDIM + c];
    const float kf = kth[640 + n * CDIM + c];
    out[OFF_CLSRA + idx] = (xr > kr) ? MASKV : atr;
    out[OFF_CLSFA + idx] = (xf > kf) ? MASKV : atf;
    out[OFF_TCAM + idx]  = (xr + OMEGAF * atr) * mul_r[c] + (xf + OMEGAF * atf) * mul_f[c];
}

extern "C" void kernel_launch(void* const* d_in, const int* in_sizes, int n_in,
                              void* d_out, int out_size, void* d_ws, size_t ws_size,
                              hipStream_t stream) {
    const float* inp    = (const float*)d_in[0];
    const float* Wfc_r  = (const float*)d_in[1];
    const float* bfc_r  = (const float*)d_in[2];
    const float* Wfc1_r = (const float*)d_in[3];
    const float* bfc1_r = (const float*)d_in[4];
    const float* Wfc_f  = (const float*)d_in[5];
    const float* bfc_f  = (const float*)d_in[6];
    const float* Wfc1_f = (const float*)d_in[7];
    const float* bfc1_f = (const float*)d_in[8];
    const float* Wcls_r = (const float*)d_in[9];
    const float* bcls_r = (const float*)d_in[10];
    const float* Wcls_f = (const float*)d_in[11];
    const float* bcls_f = (const float*)d_in[12];
    const float* Wra    = (const float*)d_in[13];
    const float* bra    = (const float*)d_in[14];
    const float* Wfa    = (const float*)d_in[15];
    const float* bfa    = (const float*)d_in[16];
    const float* mul_r  = (const float*)d_in[17];
    const float* mul_f  = (const float*)d_in[18];

    float* out = (float*)d_out;
    _Float16* wsA0 = (_Float16*)d_ws;           // 24000x1024 each
    _Float16* wsA1 = wsA0 + 24576000L;
    _Float16* wsH0 = wsA1 + 24576000L;
    _Float16* wsH1 = wsH0 + 24576000L;
    _Float16* wsW  = wsH1 + 24576000L;          // 8 x 1024x1024 f16
    float* kth = (float*)(wsW + 8L * 1048576L); // 1280 f32

    dim3 blk(256);
    dim3 gg(188, 8);

    split_f16<<<dim3(512), blk, 0, stream>>>(Wfc_r,  1024, 1024, wsW + 0L * 1048576, wsW + 1L * 1048576);
    split_f16<<<dim3(512), blk, 0, stream>>>(Wfc1_r, 1024, 1024, wsW + 2L * 1048576, wsW + 3L * 1048576);
    split_f16<<<dim3(512), blk, 0, stream>>>(Wfc_f,  1024, 1024, wsW + 4L * 1048576, wsW + 5L * 1048576);
    split_f16<<<dim3(512), blk, 0, stream>>>(Wfc1_f, 1024, 1024, wsW + 6L * 1048576, wsW + 7L * 1048576);

    // ---- RGB stream ----
    split_f16<<<dim3(2048), blk, 0, stream>>>(inp, 2 * DDIM, MDIM, wsA0, wsA1);
    gemm_split_f16<0><<<gg, blk, 0, stream>>>(wsA0, wsA1, wsW + 0L * 1048576, wsW + 1L * 1048576,
                                              bfc_r, nullptr, wsH0, wsH1);
    gemm_split_f16<1><<<gg, blk, 0, stream>>>(wsH0, wsH1, wsW + 2L * 1048576, wsW + 3L * 1048576,
                                              bfc1_r, out + OFF_XR, nullptr, nullptr);
    cls_gemm_f32<<<dim3(188), blk, 0, stream>>>(out + OFF_XR, Wcls_r, bcls_r, Wra, bra,
                                                out + OFF_CLSX_R, out + OFF_CLSRA);

    // ---- Flow stream ----
    split_f16<<<dim3(2048), blk, 0, stream>>>(inp + DDIM, 2 * DDIM, MDIM, wsA0, wsA1);
    gemm_split_f16<0><<<gg, blk, 0, stream>>>(wsA0, wsA1, wsW + 4L * 1048576, wsW + 5L * 1048576,
                                              bfc_f, nullptr, wsH0, wsH1);
    gemm_split_f16<1><<<gg, blk, 0, stream>>>(wsH0, wsH1, wsW + 6L * 1048576, wsW + 7L * 1048576,
                                              bfc1_f, out + OFF_XF, nullptr, nullptr);
    cls_gemm_f32<<<dim3(188), blk, 0, stream>>>(out + OFF_XF, Wcls_f, bcls_f, Wfa, bfa,
                                                out + OFF_CLSX_F, out + OFF_CLSFA);

    select_kth<<<dim3(1280), dim3(512), 0, stream>>>(out + OFF_CLSX_R, out + OFF_CLSX_F, kth);
    final_mask<<<dim3((NBATCH * TDIM * CDIM + 255) / 256), blk, 0, stream>>>(out, kth, mul_r, mul_f);
}

// Round 6
// 1164.374 us; speedup vs baseline: 1.0475x; 1.0475x over previous
//
#include <hip/hip_runtime.h>
#include <cstdint>

typedef _Float16 f16x8 __attribute__((ext_vector_type(8)));
typedef float f32x4 __attribute__((ext_vector_type(4)));

#define MDIM 24000   // N*T rows
#define DDIM 1024
#define CDIM 20
#define TDIM 750
#define NBATCH 32
#define KSEL 657
#define MASKV -100.0f
#define OMEGAF 0.6f
#define SPLIT_SCALE 2048.0f
#define SPLIT_INV   4.8828125e-4f   // 2^-11 exact

// d_out element offsets (x_r, cls_x_r, cls_x_ra, x_f, cls_x_f, cls_x_fa, tcam)
#define OFF_XR     0L
#define OFF_CLSX_R 24576000L
#define OFF_CLSRA  25056000L
#define OFF_XF     25536000L
#define OFF_CLSX_F 50112000L
#define OFF_CLSFA  50592000L
#define OFF_TCAM   51072000L

#define GLOAD16(g, l) __builtin_amdgcn_global_load_lds( \
    (const __attribute__((address_space(1))) void*)(g), \
    (__attribute__((address_space(3))) void*)(l), 16, 0, 0)

// ---------------------------------------------------------------------------
// split helpers
// ---------------------------------------------------------------------------
__global__ __launch_bounds__(256)
void split_f16(const float* __restrict__ src, long srcStride, long nrows,
               _Float16* __restrict__ D0, _Float16* __restrict__ D1) {
    const long nvec = nrows * 128;
    for (long v = (long)blockIdx.x * 256 + threadIdx.x; v < nvec; v += (long)gridDim.x * 256) {
        const long row = v >> 7;
        const int c8 = (int)(v & 127) << 3;
        const float4 x0 = *reinterpret_cast<const float4*>(&src[row * srcStride + c8]);
        const float4 x1 = *reinterpret_cast<const float4*>(&src[row * srcStride + c8 + 4]);
        float xs[8] = {x0.x, x0.y, x0.z, x0.w, x1.x, x1.y, x1.z, x1.w};
        f16x8 h0, h1;
#pragma unroll
        for (int j = 0; j < 8; ++j) {
            const _Float16 a = (_Float16)xs[j];
            h0[j] = a;
            h1[j] = (_Float16)((xs[j] - (float)a) * SPLIT_SCALE);
        }
        *reinterpret_cast<f16x8*>(&D0[v << 3]) = h0;
        *reinterpret_cast<f16x8*>(&D1[v << 3]) = h1;
    }
}

// ---------------------------------------------------------------------------
// Fused-panel split-f16 GEMM: ONE pass over K=1024, two accumulators.
//   accH += A0.B0 ; accL += A0.B1 + A1.B0 ; out = accH + 2^-11*accL.
// 128x128 tile, 256 thr = 4 waves (2x2), per-wave 64x64, BK=32.
// LDS: 2 buffers x 4 tiles (A0,A1,B0,B1; 128x32 f16 each) = 64 KiB.
// 16x32-f16 subtiles: one global_load_lds issue = one subtile = one MFMA
// fragment read (bijective both sides). 2-phase dbuf: stage(t+1) overlaps
// compute(t); one __syncthreads (vmcnt0+barrier) per step.
// Grid: 1504 linear, N-fastest, XCD-chunked (1504 = 8*188) so the 8 blocks
// sharing an A-tile are adjacent on one XCD's L2.
// ---------------------------------------------------------------------------
__device__ __forceinline__ void stage4(_Float16* buf,
                                       const _Float16* __restrict__ A0,
                                       const _Float16* __restrict__ A1,
                                       const _Float16* __restrict__ B0,
                                       const _Float16* __restrict__ B1,
                                       long bm, int bn, int k0,
                                       int wave, int lane) {
    const int r_in = lane >> 2;          // 0..15
    const int c8 = (lane & 3) << 3;      // 0,8,16,24 f16
#pragma unroll
    for (int h = 0; h < 2; ++h) {
        const int rb = wave * 2 + h;     // subtile 0..7
        long ra = bm + rb * 16 + r_in; if (ra > MDIM - 1) ra = MDIM - 1;
        const long rbn = (long)(bn + rb * 16 + r_in);
        const long aoff = (ra << 10) + k0 + c8;
        const long boff = (rbn << 10) + k0 + c8;
        _Float16* d = buf + rb * 512 + lane * 8;
        GLOAD16(A0 + aoff, d);
        GLOAD16(A1 + aoff, d + 4096);
        GLOAD16(B0 + boff, d + 8192);
        GLOAD16(B1 + boff, d + 12288);
    }
}

template<int MODE>
__global__ __launch_bounds__(256)
void gemm_fused_f16(const _Float16* __restrict__ A0, const _Float16* __restrict__ A1,
                    const _Float16* __restrict__ B0, const _Float16* __restrict__ B1,
                    const float* __restrict__ bias,
                    float* __restrict__ outF,
                    _Float16* __restrict__ H0, _Float16* __restrict__ H1) {
    __shared__ _Float16 sm[32768];   // 2 x 16384 f16 (A0|A1|B0|B1 tiles)
    const int t = threadIdx.x;
    const int lane = t & 63;
    const int wave = t >> 6;
    const int wr = wave >> 1, wc = wave & 1;
    const int lr = lane & 15, lk = lane >> 4;

    // XCD-chunked, N-fastest: xcd gets contiguous wg range; wg = m*8 + n
    const int bid = blockIdx.x;
    const int wg = (bid & 7) * 188 + (bid >> 3);
    const long bm = (long)(wg >> 3) * 128;
    const int bn = (wg & 7) * 128;

    f32x4 accH[4][4], accL[4][4];
#pragma unroll
    for (int mi = 0; mi < 4; ++mi)
#pragma unroll
        for (int ni = 0; ni < 4; ++ni) {
            accH[mi][ni] = (f32x4){0.f, 0.f, 0.f, 0.f};
            accL[mi][ni] = (f32x4){0.f, 0.f, 0.f, 0.f};
        }

#define LDSF(base, tileoff, rb) (*(const f16x8*)&sm[(base) + (tileoff) + (rb) * 512 + lr * 32 + lk * 8])

    stage4(sm, A0, A1, B0, B1, bm, bn, 0, wave, lane);
    __syncthreads();   // vmcnt(0) drain + barrier: buf0 ready

    for (int step = 0; step < 32; ++step) {
        const int cur = (step & 1) * 16384;
        if (step < 31)
            stage4(sm + ((step + 1) & 1) * 16384, A0, A1, B0, B1,
                   bm, bn, (step + 1) * 32, wave, lane);

        f16x8 av0[4], av1[4], bv0[4], bv1[4];
#pragma unroll
        for (int mi = 0; mi < 4; ++mi) av0[mi] = LDSF(cur, 0, wr * 4 + mi);
#pragma unroll
        for (int ni = 0; ni < 4; ++ni) bv0[ni] = LDSF(cur, 8192, wc * 4 + ni);
#pragma unroll
        for (int mi = 0; mi < 4; ++mi)
#pragma unroll
            for (int ni = 0; ni < 4; ++ni)
                accH[mi][ni] = __builtin_amdgcn_mfma_f32_16x16x32_f16(av0[mi], bv0[ni], accH[mi][ni], 0, 0, 0);
#pragma unroll
        for (int ni = 0; ni < 4; ++ni) bv1[ni] = LDSF(cur, 12288, wc * 4 + ni);
#pragma unroll
        for (int mi = 0; mi < 4; ++mi)
#pragma unroll
            for (int ni = 0; ni < 4; ++ni)
                accL[mi][ni] = __builtin_amdgcn_mfma_f32_16x16x32_f16(av0[mi], bv1[ni], accL[mi][ni], 0, 0, 0);
#pragma unroll
        for (int mi = 0; mi < 4; ++mi) av1[mi] = LDSF(cur, 4096, wr * 4 + mi);
#pragma unroll
        for (int mi = 0; mi < 4; ++mi)
#pragma unroll
            for (int ni = 0; ni < 4; ++ni)
                accL[mi][ni] = __builtin_amdgcn_mfma_f32_16x16x32_f16(av1[mi], bv0[ni], accL[mi][ni], 0, 0, 0);

        __syncthreads();   // next buf landed; cur reads done before overwrite
    }

    // epilogue: C/D layout col=lane&15, row=(lane>>4)*4+r (verified r2/r4/r5)
#pragma unroll
    for (int ni = 0; ni < 4; ++ni) {
        const int col = bn + wc * 64 + ni * 16 + lr;
        const float bb = bias[col];
#pragma unroll
        for (int mi = 0; mi < 4; ++mi) {
            const long rbase = bm + wr * 64 + mi * 16 + lk * 4;
#pragma unroll
            for (int r = 0; r < 4; ++r) {
                const long row = rbase + r;
                if (row < MDIM) {
                    const float v = accH[mi][ni][r] + SPLIT_INV * accL[mi][ni][r];
                    const float hv = fmaxf(v + bb, 0.f);
                    if (MODE == 0) {
                        const _Float16 h0 = (_Float16)hv;
                        H0[row * DDIM + col] = h0;
                        H1[row * DDIM + col] = (_Float16)((hv - (float)h0) * SPLIT_SCALE);
                    } else {
                        outF[row * DDIM + col] = hv;
                    }
                }
            }
        }
    }
#undef LDSF
}

// ---------------------------------------------------------------------------
// cls/at heads in fp32 (precision-critical for the top-k mask), N padded to 48.
// ---------------------------------------------------------------------------
__global__ __launch_bounds__(256)
void cls_gemm_f32(const float* __restrict__ H,
                  const float* __restrict__ Wc, const float* __restrict__ bc,
                  const float* __restrict__ Wa, const float* __restrict__ ba,
                  float* __restrict__ clsx, float* __restrict__ atout) {
    __shared__ float As[16][140];
    __shared__ float Bs[16][48];
    const int tid = threadIdx.x;
    const int tx = tid & 15, ty = tid >> 4;
    const long bm = (long)blockIdx.x * 128;

    float acc[8][3];
#pragma unroll
    for (int i = 0; i < 8; ++i)
#pragma unroll
        for (int j = 0; j < 3; ++j) acc[i][j] = 0.f;

    for (int k0 = 0; k0 < DDIM; k0 += 16) {
        __syncthreads();
#pragma unroll
        for (int h = 0; h < 2; ++h) {
            const int c = tid + h * 256;
            const int row = c >> 2;
            const int kc = (c & 3) << 2;
            long ar = bm + row; if (ar > MDIM - 1) ar = MDIM - 1;
            const float4 va = *reinterpret_cast<const float4*>(&H[ar * DDIM + k0 + kc]);
            As[kc + 0][row] = va.x; As[kc + 1][row] = va.y;
            As[kc + 2][row] = va.z; As[kc + 3][row] = va.w;
        }
        if (tid < 192) {
            const int n = tid >> 2;
            const int kc = (tid & 3) << 2;
            float4 w = make_float4(0.f, 0.f, 0.f, 0.f);
            if (n < 20)      w = *reinterpret_cast<const float4*>(&Wc[(long)n * DDIM + k0 + kc]);
            else if (n < 40) w = *reinterpret_cast<const float4*>(&Wa[(long)(n - 20) * DDIM + k0 + kc]);
            Bs[kc + 0][n] = w.x; Bs[kc + 1][n] = w.y;
            Bs[kc + 2][n] = w.z; Bs[kc + 3][n] = w.w;
        }
        __syncthreads();
#pragma unroll
        for (int kk = 0; kk < 16; ++kk) {
            float a[8];
            *(float4*)&a[0] = *(const float4*)&As[kk][ty * 8];
            *(float4*)&a[4] = *(const float4*)&As[kk][ty * 8 + 4];
            const float b0 = Bs[kk][tx];
            const float b1 = Bs[kk][tx + 16];
            const float b2 = Bs[kk][tx + 32];
#pragma unroll
            for (int i = 0; i < 8; ++i) {
                acc[i][0] = fmaf(a[i], b0, acc[i][0]);
                acc[i][1] = fmaf(a[i], b1, acc[i][1]);
                acc[i][2] = fmaf(a[i], b2, acc[i][2]);
            }
        }
    }

#pragma unroll
    for (int j = 0; j < 3; ++j) {
        const int col = tx + 16 * j;
        const bool isC = (col < 20);
        const bool isA = (col >= 20) && (col < 40);
        const float bvv = isC ? bc[col] : (isA ? ba[col - 20] : 0.f);
#pragma unroll
        for (int i = 0; i < 8; ++i) {
            const long row = bm + ty * 8 + i;
            if (row < MDIM) {
                const float v = acc[i][j] + bvv;
                if (isC)      clsx[row * CDIM + col] = v;
                else if (isA) atout[row * CDIM + col - 20] = v;
            }
        }
    }
}

// Per (stream,n,c): bitonic sort 750 values (pad to 1024 with +inf), emit rank KSEL.
__global__ __launch_bounds__(512)
void select_kth(const float* __restrict__ clsx_r, const float* __restrict__ clsx_f,
                float* __restrict__ kth) {
    __shared__ float s[1024];
    const int b = blockIdx.x;
    const int z = b / 640;
    const int rem = b - z * 640;
    const int n = rem / CDIM;
    const int c = rem - n * CDIM;
    const float* src = (z == 0) ? clsx_r : clsx_f;
    const int tid = threadIdx.x;

    for (int i = tid; i < 1024; i += 512)
        s[i] = (i < TDIM) ? src[((long)n * TDIM + i) * CDIM + c] : 3.402823466e38f;
    __syncthreads();

    for (int k = 2; k <= 1024; k <<= 1) {
        for (int j = k >> 1; j > 0; j >>= 1) {
            for (int i = tid; i < 1024; i += 512) {
                const int ixj = i ^ j;
                if (ixj > i) {
                    const bool up = ((i & k) == 0);
                    const float x = s[i], y = s[ixj];
                    if ((x > y) == up) { s[i] = y; s[ixj] = x; }
                }
            }
            __syncthreads();
        }
    }
    if (tid == 0) kth[b] = s[KSEL - 1];
}

__global__ __launch_bounds__(256)
void final_mask(float* __restrict__ out, const float* __restrict__ kth,
                const float* __restrict__ mul_r, const float* __restrict__ mul_f) {
    const int idx = blockIdx.x * 256 + threadIdx.x;
    if (idx >= NBATCH * TDIM * CDIM) return;
    const int m = idx / CDIM;
    const int c = idx - m * CDIM;
    const int n = m / TDIM;
    const float xr  = out[OFF_CLSX_R + idx];
    const float xf  = out[OFF_CLSX_F + idx];
    const float atr = out[OFF_CLSRA + idx];
    const float atf = out[OFF_CLSFA + idx];
    const float kr = kth[n * CDIM + c];
    const float kf = kth[640 + n * CDIM + c];
    out[OFF_CLSRA + idx] = (xr > kr) ? MASKV : atr;
    out[OFF_CLSFA + idx] = (xf > kf) ? MASKV : atf;
    out[OFF_TCAM + idx]  = (xr + OMEGAF * atr) * mul_r[c] + (xf + OMEGAF * atf) * mul_f[c];
}

extern "C" void kernel_launch(void* const* d_in, const int* in_sizes, int n_in,
                              void* d_out, int out_size, void* d_ws, size_t ws_size,
                              hipStream_t stream) {
    const float* inp    = (const float*)d_in[0];
    const float* Wfc_r  = (const float*)d_in[1];
    const float* bfc_r  = (const float*)d_in[2];
    const float* Wfc1_r = (const float*)d_in[3];
    const float* bfc1_r = (const float*)d_in[4];
    const float* Wfc_f  = (const float*)d_in[5];
    const float* bfc_f  = (const float*)d_in[6];
    const float* Wfc1_f = (const float*)d_in[7];
    const float* bfc1_f = (const float*)d_in[8];
    const float* Wcls_r = (const float*)d_in[9];
    const float* bcls_r = (const float*)d_in[10];
    const float* Wcls_f = (const float*)d_in[11];
    const float* bcls_f = (const float*)d_in[12];
    const float* Wra    = (const float*)d_in[13];
    const float* bra    = (const float*)d_in[14];
    const float* Wfa    = (const float*)d_in[15];
    const float* bfa    = (const float*)d_in[16];
    const float* mul_r  = (const float*)d_in[17];
    const float* mul_f  = (const float*)d_in[18];

    float* out = (float*)d_out;
    _Float16* wsA0 = (_Float16*)d_ws;           // 24000x1024 each
    _Float16* wsA1 = wsA0 + 24576000L;
    _Float16* wsH0 = wsA1 + 24576000L;
    _Float16* wsH1 = wsH0 + 24576000L;
    _Float16* wsW  = wsH1 + 24576000L;          // 8 x 1024x1024 f16
    float* kth = (float*)(wsW + 8L * 1048576L); // 1280 f32

    dim3 blk(256);
    dim3 gg(1504);

    split_f16<<<dim3(512), blk, 0, stream>>>(Wfc_r,  1024, 1024, wsW + 0L * 1048576, wsW + 1L * 1048576);
    split_f16<<<dim3(512), blk, 0, stream>>>(Wfc1_r, 1024, 1024, wsW + 2L * 1048576, wsW + 3L * 1048576);
    split_f16<<<dim3(512), blk, 0, stream>>>(Wfc_f,  1024, 1024, wsW + 4L * 1048576, wsW + 5L * 1048576);
    split_f16<<<dim3(512), blk, 0, stream>>>(Wfc_f == nullptr ? Wfc_f : Wfc1_f, 1024, 1024, wsW + 6L * 1048576, wsW + 7L * 1048576);

    // ---- RGB stream ----
    split_f16<<<dim3(2048), blk, 0, stream>>>(inp, 2 * DDIM, MDIM, wsA0, wsA1);
    gemm_fused_f16<0><<<gg, blk, 0, stream>>>(wsA0, wsA1, wsW + 0L * 1048576, wsW + 1L * 1048576,
                                              bfc_r, nullptr, wsH0, wsH1);
    gemm_fused_f16<1><<<gg, blk, 0, stream>>>(wsH0, wsH1, wsW + 2L * 1048576, wsW + 3L * 1048576,
                                              bfc1_r, out + OFF_XR, nullptr, nullptr);
    cls_gemm_f32<<<dim3(188), blk, 0, stream>>>(out + OFF_XR, Wcls_r, bcls_r, Wra, bra,
                                                out + OFF_CLSX_R, out + OFF_CLSRA);

    // ---- Flow stream ----
    split_f16<<<dim3(2048), blk, 0, stream>>>(inp + DDIM, 2 * DDIM, MDIM, wsA0, wsA1);
    gemm_fused_f16<0><<<gg, blk, 0, stream>>>(wsA0, wsA1, wsW + 4L * 1048576, wsW + 5L * 1048576,
                                              bfc_f, nullptr, wsH0, wsH1);
    gemm_fused_f16<1><<<gg, blk, 0, stream>>>(wsH0, wsH1, wsW + 6L * 1048576, wsW + 7L * 1048576,
                                              bfc1_f, out + OFF_XF, nullptr, nullptr);
    cls_gemm_f32<<<dim3(188), blk, 0, stream>>>(out + OFF_XF, Wcls_f, bcls_f, Wfa, bfa,
                                                out + OFF_CLSX_F, out + OFF_CLSFA);

    select_kth<<<dim3(1280), dim3(512), 0, stream>>>(out + OFF_CLSX_R, out + OFF_CLSX_F, kth);
    final_mask<<<dim3((NBATCH * TDIM * CDIM + 255) / 256), blk, 0, stream>>>(out, kth, mul_r, mul_f);
}

// Round 8
// 1005.867 us; speedup vs baseline: 1.2126x; 1.1576x over previous
//
#include <hip/hip_runtime.h>
#include <cstdint>

typedef _Float16 f16x8 __attribute__((ext_vector_type(8)));
typedef float f32x4 __attribute__((ext_vector_type(4)));

#define MDIM 24000   // N*T rows
#define DDIM 1024
#define CDIM 20
#define TDIM 750
#define NBATCH 32
#define KSEL 657
#define MASKV -100.0f
#define OMEGAF 0.6f
#define SPLIT_SCALE 2048.0f
#define SPLIT_INV   4.8828125e-4f   // 2^-11 exact

// d_out element offsets (x_r, cls_x_r, cls_x_ra, x_f, cls_x_f, cls_x_fa, tcam)
#define OFF_XR     0L
#define OFF_CLSX_R 24576000L
#define OFF_CLSRA  25056000L
#define OFF_XF     25536000L
#define OFF_CLSX_F 50112000L
#define OFF_CLSFA  50592000L
#define OFF_TCAM   51072000L

#define GLOAD16(g, l) __builtin_amdgcn_global_load_lds( \
    (const __attribute__((address_space(1))) void*)(g), \
    (__attribute__((address_space(3))) void*)(l), 16, 0, 0)

#define SBAR0() __builtin_amdgcn_sched_barrier(0)

// ---------------------------------------------------------------------------
// split helpers
// ---------------------------------------------------------------------------
__global__ __launch_bounds__(256)
void split_f16(const float* __restrict__ src, long srcStride, long nrows,
               _Float16* __restrict__ D0, _Float16* __restrict__ D1) {
    const long nvec = nrows * 128;
    for (long v = (long)blockIdx.x * 256 + threadIdx.x; v < nvec; v += (long)gridDim.x * 256) {
        const long row = v >> 7;
        const int c8 = (int)(v & 127) << 3;
        const float4 x0 = *reinterpret_cast<const float4*>(&src[row * srcStride + c8]);
        const float4 x1 = *reinterpret_cast<const float4*>(&src[row * srcStride + c8 + 4]);
        float xs[8] = {x0.x, x0.y, x0.z, x0.w, x1.x, x1.y, x1.z, x1.w};
        f16x8 h0, h1;
#pragma unroll
        for (int j = 0; j < 8; ++j) {
            const _Float16 a = (_Float16)xs[j];
            h0[j] = a;
            h1[j] = (_Float16)((xs[j] - (float)a) * SPLIT_SCALE);
        }
        *reinterpret_cast<f16x8*>(&D0[v << 3]) = h0;
        *reinterpret_cast<f16x8*>(&D1[v << 3]) = h1;
    }
}

// ---------------------------------------------------------------------------
// Fused-panel split-f16 GEMM, counted-vmcnt 2-deep pipeline.
//   accH += A0.B0 ; accL += A0.B1 + A1.B0 ; out = accH + 2^-11*accL.
// 128x128 tile, 256 thr = 4 waves (2x2), per-wave 64x64, BK=32.
// LDS: 2 buf x 4 tiles (A0,A1,B0,B1; 128x32 f16) = 64 KiB -> 2 blocks/CU.
// Per iter t: STAGE(t+1) -> vmcnt(8) [tile t's 8 loads landed] -> barrier A
// -> 16 ds_read_b128 -> lgkmcnt(0) -> barrier B (overwrite-safe) -> 48 MFMA.
// RACE FIX (r7 post-mortem): raw s_barrier is NOT a compiler memory fence;
// ds_reads were hoistable above barrier A (reading other waves' un-landed
// subtiles) and stage-writes above barrier B (clobbering un-read data).
// Every barrier/waitcnt is now bracketed with sched_barrier(0) -- compile-
// time pins only, the HW pipeline (loads in flight across barriers) remains.
// ---------------------------------------------------------------------------
template<int MODE>
__global__ __launch_bounds__(256, 2)
void gemm_fused_f16(const _Float16* __restrict__ A0, const _Float16* __restrict__ A1,
                    const _Float16* __restrict__ B0, const _Float16* __restrict__ B1,
                    const float* __restrict__ bias,
                    float* __restrict__ outF,
                    _Float16* __restrict__ H0, _Float16* __restrict__ H1) {
    __shared__ _Float16 sm[32768];   // 2 x 16384 f16 (A0|A1|B0|B1 tiles)
    const int t = threadIdx.x;
    const int lane = t & 63;
    const int wave = t >> 6;
    const int wr = wave >> 1, wc = wave & 1;
    const int lr = lane & 15, lk = lane >> 4;
    const int wr4 = wr * 4, wc4 = wc * 4;

    // XCD-chunked, N-fastest: 1504 = 8 XCD chunks of 188; wg = m*8 + n
    const int bid = blockIdx.x;
    const int wg = (bid & 7) * 188 + (bid >> 3);
    const long bm = (long)(wg >> 3) * 128;
    const int bn = (wg & 7) * 128;

    // hoisted stage addressing (rows are loop-invariant; only k advances)
    const int r_in = lane >> 2;          // 0..15
    const int c8 = (lane & 3) << 3;      // 0,8,16,24 f16
    long ra0 = bm + (wave * 2 + 0) * 16 + r_in; if (ra0 > MDIM - 1) ra0 = MDIM - 1;
    long ra1 = bm + (wave * 2 + 1) * 16 + r_in; if (ra1 > MDIM - 1) ra1 = MDIM - 1;
    const long rb0 = (long)(bn + (wave * 2 + 0) * 16 + r_in);
    const long rb1 = (long)(bn + (wave * 2 + 1) * 16 + r_in);
    const _Float16* pA0a = A0 + (ra0 << 10) + c8;
    const _Float16* pA0b = A0 + (ra1 << 10) + c8;
    const _Float16* pA1a = A1 + (ra0 << 10) + c8;
    const _Float16* pA1b = A1 + (ra1 << 10) + c8;
    const _Float16* pB0a = B0 + (rb0 << 10) + c8;
    const _Float16* pB0b = B0 + (rb1 << 10) + c8;
    const _Float16* pB1a = B1 + (rb0 << 10) + c8;
    const _Float16* pB1b = B1 + (rb1 << 10) + c8;
    const int sb0 = (wave * 2 + 0) * 512 + lane * 8;
    const int sb1 = (wave * 2 + 1) * 512 + lane * 8;

#define STAGE8(par) do { \
    _Float16* _d = sm + (par) * 16384; \
    GLOAD16(pA0a, _d + sb0);         GLOAD16(pA0b, _d + sb1); \
    GLOAD16(pA1a, _d + 4096 + sb0);  GLOAD16(pA1b, _d + 4096 + sb1); \
    GLOAD16(pB0a, _d + 8192 + sb0);  GLOAD16(pB0b, _d + 8192 + sb1); \
    GLOAD16(pB1a, _d + 12288 + sb0); GLOAD16(pB1b, _d + 12288 + sb1); \
    pA0a += 32; pA0b += 32; pA1a += 32; pA1b += 32; \
    pB0a += 32; pB0b += 32; pB1a += 32; pB1b += 32; \
} while (0)

#define LDSF(tileoff, rb) (*(const f16x8*)&sm[cur + (tileoff) + (rb) * 512 + lr * 32 + lk * 8])

    f32x4 accH[4][4], accL[4][4];
#pragma unroll
    for (int mi = 0; mi < 4; ++mi)
#pragma unroll
        for (int ni = 0; ni < 4; ++ni) {
            accH[mi][ni] = (f32x4){0.f, 0.f, 0.f, 0.f};
            accL[mi][ni] = (f32x4){0.f, 0.f, 0.f, 0.f};
        }

    f16x8 av0[4], av1[4], bv0[4], bv1[4];

#define COMPUTE() do { \
    SBAR0(); /* pin: reads stay AFTER barrier A */ \
    _Pragma("unroll") for (int mi = 0; mi < 4; ++mi) av0[mi] = LDSF(0,     wr4 + mi); \
    _Pragma("unroll") for (int mi = 0; mi < 4; ++mi) av1[mi] = LDSF(4096,  wr4 + mi); \
    _Pragma("unroll") for (int ni = 0; ni < 4; ++ni) bv0[ni] = LDSF(8192,  wc4 + ni); \
    _Pragma("unroll") for (int ni = 0; ni < 4; ++ni) bv1[ni] = LDSF(12288, wc4 + ni); \
    asm volatile("s_waitcnt lgkmcnt(0)" ::: "memory"); \
    SBAR0(); \
    __builtin_amdgcn_s_barrier();  /* B: all waves consumed cur buf */ \
    SBAR0(); /* pin: MFMAs + next stage stay AFTER barrier B */ \
    _Pragma("unroll") for (int mi = 0; mi < 4; ++mi) \
    _Pragma("unroll") for (int ni = 0; ni < 4; ++ni) \
        accH[mi][ni] = __builtin_amdgcn_mfma_f32_16x16x32_f16(av0[mi], bv0[ni], accH[mi][ni], 0, 0, 0); \
    _Pragma("unroll") for (int mi = 0; mi < 4; ++mi) \
    _Pragma("unroll") for (int ni = 0; ni < 4; ++ni) \
        accL[mi][ni] = __builtin_amdgcn_mfma_f32_16x16x32_f16(av0[mi], bv1[ni], accL[mi][ni], 0, 0, 0); \
    _Pragma("unroll") for (int mi = 0; mi < 4; ++mi) \
    _Pragma("unroll") for (int ni = 0; ni < 4; ++ni) \
        accL[mi][ni] = __builtin_amdgcn_mfma_f32_16x16x32_f16(av1[mi], bv0[ni], accL[mi][ni], 0, 0, 0); \
} while (0)

    STAGE8(0);                       // tile 0 -> buf0 (8 loads in flight)
    for (int step = 0; step < 31; ++step) {
        const int cur = (step & 1) * 16384;
        STAGE8((step + 1) & 1);      // tile t+1 (8 newest loads)
        SBAR0();                     // pin: stage issued before the wait
        asm volatile("s_waitcnt vmcnt(8)" ::: "memory");  // tile t landed
        SBAR0();
        __builtin_amdgcn_s_barrier();                     // A: cur buf ready
        COMPUTE();
    }
    {   // peeled last step: nothing left to stage, drain tile 31 fully
        const int cur = 16384;
        asm volatile("s_waitcnt vmcnt(0)" ::: "memory");
        SBAR0();
        __builtin_amdgcn_s_barrier();
        COMPUTE();
    }

    // epilogue: C/D layout col=lane&15, row=(lane>>4)*4+r (verified r2/r4/r5)
#pragma unroll
    for (int ni = 0; ni < 4; ++ni) {
        const int col = bn + wc * 64 + ni * 16 + lr;
        const float bb = bias[col];
#pragma unroll
        for (int mi = 0; mi < 4; ++mi) {
            const long rbase = bm + wr * 64 + mi * 16 + lk * 4;
#pragma unroll
            for (int r = 0; r < 4; ++r) {
                const long row = rbase + r;
                if (row < MDIM) {
                    const float v = accH[mi][ni][r] + SPLIT_INV * accL[mi][ni][r];
                    const float hv = fmaxf(v + bb, 0.f);
                    if (MODE == 0) {
                        const _Float16 h0 = (_Float16)hv;
                        H0[row * DDIM + col] = h0;
                        H1[row * DDIM + col] = (_Float16)((hv - (float)h0) * SPLIT_SCALE);
                    } else {
                        outF[row * DDIM + col] = hv;
                    }
                }
            }
        }
    }
#undef COMPUTE
#undef LDSF
#undef STAGE8
}

// ---------------------------------------------------------------------------
// cls/at heads in fp32 (precision-critical for the top-k mask), N padded to 48.
// M-tile 64 -> 376 blocks (fills 256 CUs better than 188).
// ---------------------------------------------------------------------------
__global__ __launch_bounds__(256)
void cls_gemm_f32(const float* __restrict__ H,
                  const float* __restrict__ Wc, const float* __restrict__ bc,
                  const float* __restrict__ Wa, const float* __restrict__ ba,
                  float* __restrict__ clsx, float* __restrict__ atout) {
    __shared__ float As[16][72];
    __shared__ float Bs[16][48];
    const int tid = threadIdx.x;
    const int tx = tid & 15, ty = tid >> 4;
    const long bm = (long)blockIdx.x * 64;

    float acc[4][3];
#pragma unroll
    for (int i = 0; i < 4; ++i)
#pragma unroll
        for (int j = 0; j < 3; ++j) acc[i][j] = 0.f;

    for (int k0 = 0; k0 < DDIM; k0 += 16) {
        __syncthreads();
        {
            const int row = tid >> 2;            // 0..63
            const int kc = (tid & 3) << 2;       // 0,4,8,12
            long ar = bm + row; if (ar > MDIM - 1) ar = MDIM - 1;
            const float4 va = *reinterpret_cast<const float4*>(&H[ar * DDIM + k0 + kc]);
            As[kc + 0][row] = va.x; As[kc + 1][row] = va.y;
            As[kc + 2][row] = va.z; As[kc + 3][row] = va.w;
        }
        if (tid < 192) {
            const int n = tid >> 2;
            const int kc = (tid & 3) << 2;
            float4 w = make_float4(0.f, 0.f, 0.f, 0.f);
            if (n < 20)      w = *reinterpret_cast<const float4*>(&Wc[(long)n * DDIM + k0 + kc]);
            else if (n < 40) w = *reinterpret_cast<const float4*>(&Wa[(long)(n - 20) * DDIM + k0 + kc]);
            Bs[kc + 0][n] = w.x; Bs[kc + 1][n] = w.y;
            Bs[kc + 2][n] = w.z; Bs[kc + 3][n] = w.w;
        }
        __syncthreads();
#pragma unroll
        for (int kk = 0; kk < 16; ++kk) {
            float a[4];
            *(float4*)&a[0] = *(const float4*)&As[kk][ty * 4];
            const float b0 = Bs[kk][tx];
            const float b1 = Bs[kk][tx + 16];
            const float b2 = Bs[kk][tx + 32];
#pragma unroll
            for (int i = 0; i < 4; ++i) {
                acc[i][0] = fmaf(a[i], b0, acc[i][0]);
                acc[i][1] = fmaf(a[i], b1, acc[i][1]);
                acc[i][2] = fmaf(a[i], b2, acc[i][2]);
            }
        }
    }

#pragma unroll
    for (int j = 0; j < 3; ++j) {
        const int col = tx + 16 * j;
        const bool isC = (col < 20);
        const bool isA = (col >= 20) && (col < 40);
        const float bvv = isC ? bc[col] : (isA ? ba[col - 20] : 0.f);
#pragma unroll
        for (int i = 0; i < 4; ++i) {
            const long row = bm + ty * 4 + i;
            if (row < MDIM) {
                const float v = acc[i][j] + bvv;
                if (isC)      clsx[row * CDIM + col] = v;
                else if (isA) atout[row * CDIM + col - 20] = v;
            }
        }
    }
}

// Per (stream,n,c): bitonic sort 750 values (pad to 1024 with +inf), emit rank KSEL.
__global__ __launch_bounds__(512)
void select_kth(const float* __restrict__ clsx_r, const float* __restrict__ clsx_f,
                float* __restrict__ kth) {
    __shared__ float s[1024];
    const int b = blockIdx.x;
    const int z = b / 640;
    const int rem = b - z * 640;
    const int n = rem / CDIM;
    const int c = rem - n * CDIM;
    const float* src = (z == 0) ? clsx_r : clsx_f;
    const int tid = threadIdx.x;

    for (int i = tid; i < 1024; i += 512)
        s[i] = (i < TDIM) ? src[((long)n * TDIM + i) * CDIM + c] : 3.402823466e38f;
    __syncthreads();

    for (int k = 2; k <= 1024; k <<= 1) {
        for (int j = k >> 1; j > 0; j >>= 1) {
            for (int i = tid; i < 1024; i += 512) {
                const int ixj = i ^ j;
                if (ixj > i) {
                    const bool up = ((i & k) == 0);
                    const float x = s[i], y = s[ixj];
                    if ((x > y) == up) { s[i] = y; s[ixj] = x; }
                }
            }
            __syncthreads();
        }
    }
    if (tid == 0) kth[b] = s[KSEL - 1];
}

__global__ __launch_bounds__(256)
void final_mask(float* __restrict__ out, const float* __restrict__ kth,
                const float* __restrict__ mul_r, const float* __restrict__ mul_f) {
    const int idx = blockIdx.x * 256 + threadIdx.x;
    if (idx >= NBATCH * TDIM * CDIM) return;
    const int m = idx / CDIM;
    const int c = idx - m * CDIM;
    const int n = m / TDIM;
    const float xr  = out[OFF_CLSX_R + idx];
    const float xf  = out[OFF_CLSX_F + idx];
    const float atr = out[OFF_CLSRA + idx];
    const float atf = out[OFF_CLSFA + idx];
    const float kr = kth[n * CDIM + c];
    const float kf = kth[640 + n * CDIM + c];
    out[OFF_CLSRA + idx] = (xr > kr) ? MASKV : atr;
    out[OFF_CLSFA + idx] = (xf > kf) ? MASKV : atf;
    out[OFF_TCAM + idx]  = (xr + OMEGAF * atr) * mul_r[c] + (xf + OMEGAF * atf) * mul_f[c];
}

extern "C" void kernel_launch(void* const* d_in, const int* in_sizes, int n_in,
                              void* d_out, int out_size, void* d_ws, size_t ws_size,
                              hipStream_t stream) {
    const float* inp    = (const float*)d_in[0];
    const float* Wfc_r  = (const float*)d_in[1];
    const float* bfc_r  = (const float*)d_in[2];
    const float* Wfc1_r = (const float*)d_in[3];
    const float* bfc1_r = (const float*)d_in[4];
    const float* Wfc_f  = (const float*)d_in[5];
    const float* bfc_f  = (const float*)d_in[6];
    const float* Wfc1_f = (const float*)d_in[7];
    const float* bfc1_f = (const float*)d_in[8];
    const float* Wcls_r = (const float*)d_in[9];
    const float* bcls_r = (const float*)d_in[10];
    const float* Wcls_f = (const float*)d_in[11];
    const float* bcls_f = (const float*)d_in[12];
    const float* Wra    = (const float*)d_in[13];
    const float* bra    = (const float*)d_in[14];
    const float* Wfa    = (const float*)d_in[15];
    const float* bfa    = (const float*)d_in[16];
    const float* mul_r  = (const float*)d_in[17];
    const float* mul_f  = (const float*)d_in[18];

    float* out = (float*)d_out;
    _Float16* wsA0 = (_Float16*)d_ws;           // 24000x1024 each
    _Float16* wsA1 = wsA0 + 24576000L;
    _Float16* wsH0 = wsA1 + 24576000L;
    _Float16* wsH1 = wsH0 + 24576000L;
    _Float16* wsW  = wsH1 + 24576000L;          // 8 x 1024x1024 f16
    float* kth = (float*)(wsW + 8L * 1048576L); // 1280 f32

    dim3 blk(256);
    dim3 gg(1504);

    split_f16<<<dim3(512), blk, 0, stream>>>(Wfc_r,  1024, 1024, wsW + 0L * 1048576, wsW + 1L * 1048576);
    split_f16<<<dim3(512), blk, 0, stream>>>(Wfc1_r, 1024, 1024, wsW + 2L * 1048576, wsW + 3L * 1048576);
    split_f16<<<dim3(512), blk, 0, stream>>>(Wfc_f,  1024, 1024, wsW + 4L * 1048576, wsW + 5L * 1048576);
    split_f16<<<dim3(512), blk, 0, stream>>>(Wfc1_f, 1024, 1024, wsW + 6L * 1048576, wsW + 7L * 1048576);

    // ---- RGB stream ----
    split_f16<<<dim3(2048), blk, 0, stream>>>(inp, 2 * DDIM, MDIM, wsA0, wsA1);
    gemm_fused_f16<0><<<gg, blk, 0, stream>>>(wsA0, wsA1, wsW + 0L * 1048576, wsW + 1L * 1048576,
                                              bfc_r, nullptr, wsH0, wsH1);
    gemm_fused_f16<1><<<gg, blk, 0, stream>>>(wsH0, wsH1, wsW + 2L * 1048576, wsW + 3L * 1048576,
                                              bfc1_r, out + OFF_XR, nullptr, nullptr);
    cls_gemm_f32<<<dim3(376), blk, 0, stream>>>(out + OFF_XR, Wcls_r, bcls_r, Wra, bra,
                                                out + OFF_CLSX_R, out + OFF_CLSRA);

    // ---- Flow stream ----
    split_f16<<<dim3(2048), blk, 0, stream>>>(inp + DDIM, 2 * DDIM, MDIM, wsA0, wsA1);
    gemm_fused_f16<0><<<gg, blk, 0, stream>>>(wsA0, wsA1, wsW + 4L * 1048576, wsW + 5L * 1048576,
                                              bfc_f, nullptr, wsH0, wsH1);
    gemm_fused_f16<1><<<gg, blk, 0, stream>>>(wsH0, wsH1, wsW + 6L * 1048576, wsW + 7L * 1048576,
                                              bfc1_f, out + OFF_XF, nullptr, nullptr);
    cls_gemm_f32<<<dim3(376), blk, 0, stream>>>(out + OFF_XF, Wcls_f, bcls_f, Wfa, bfa,
                                                out + OFF_CLSX_F, out + OFF_CLSFA);

    select_kth<<<dim3(1280), dim3(512), 0, stream>>>(out + OFF_CLSX_R, out + OFF_CLSX_F, kth);
    final_mask<<<dim3((NBATCH * TDIM * CDIM + 255) / 256), blk, 0, stream>>>(out, kth, mul_r, mul_f);
}